// Round 1
// baseline (945.444 us; speedup 1.0000x reference)
//
#include <hip/hip_runtime.h>

#define NF   16
#define BSZ  32768
#define EDIM 64
#define ODIM 64
#define HID  128
#define HASH 200000u

#define SA 72    // emb / W1T row stride (bf16 elems): 144 B -> 2-way bank alias (free)
#define SH 136   // H / W2T row stride: 272 B -> 2-way bank alias (free)

typedef __attribute__((ext_vector_type(8))) short bf16x8;
typedef __attribute__((ext_vector_type(4))) float f32x4;

__device__ __forceinline__ short f2bf(float f) {
    union { float f; unsigned u; } v; v.f = f;
    unsigned r = v.u + 0x7FFFu + ((v.u >> 16) & 1u);   // RNE
    return (short)(r >> 16);
}

__global__ __launch_bounds__(256, 2) void sparse_arch_kernel(
    const int*   __restrict__ inputs,  // [B, F] int32
    const float* __restrict__ tables,  // [F, HASH, E]
    const float* __restrict__ W1,      // [F, E, HID]
    const float* __restrict__ b1,      // [F, HID]
    const float* __restrict__ W2,      // [F, HID, O]
    const float* __restrict__ b2,      // [F, O]
    float*       __restrict__ out)     // [F, B, O]
{
    __shared__ __align__(16) short W1T[HID * SA];     // W1T[h][e] bf16
    __shared__ __align__(16) short W2T[ODIM * SH];    // W2T[o][h] bf16
    __shared__ __align__(16) short EMB[2][64 * SA];   // emb[m][e] bf16, dbuf
    __shared__ __align__(16) short Hs[64 * SH];       // H[m][h] bf16
    __shared__ __align__(16) float b1s[HID];
    __shared__ __align__(16) float b2s[ODIM];

    const int t      = threadIdx.x;
    const int f      = blockIdx.x >> 5;   // 16 features
    const int blk    = blockIdx.x & 31;   // 32 blocks/feature
    const int b0base = blk * 1024;        // 16 tiles x 64 rows per block

    // ---- stage weights (once per block; sources are L2-resident, 1 MB total) ----
    const float* W1f = W1 + (size_t)f * (EDIM * HID);
    for (int i = t; i < EDIM * HID; i += 256) {
        int e = i >> 7, h = i & 127;                  // W1[e][h] -> W1T[h][e]
        W1T[h * SA + e] = f2bf(W1f[i]);
    }
    const float* W2f = W2 + (size_t)f * (HID * ODIM);
    for (int i = t; i < HID * ODIM; i += 256) {
        int h = i >> 6, o = i & 63;                   // W2[h][o] -> W2T[o][h]
        W2T[o * SH + h] = f2bf(W2f[i]);
    }
    if (t < HID)  b1s[t] = b1[f * HID + t];
    if (t < ODIM) b2s[t] = b2[f * ODIM + t];

    // ---- gather assignment: 4 threads per row, 16 floats (4x float4) each ----
    const int gr = t >> 2;     // row in tile (0..63)
    const int gq = t & 3;      // quarter of the 64-float row
    const float* tabf = tables + (size_t)f * HASH * EDIM;

    float4 pf[4];
    {   // prefetch tile 0
        int b = b0base + gr;
        unsigned idx = (unsigned)(inputs[b * NF + f] + 1) % HASH;
        const float4* src = (const float4*)(tabf + (size_t)idx * EDIM) + gq * 4;
        pf[0] = src[0]; pf[1] = src[1]; pf[2] = src[2]; pf[3] = src[3];
    }

    const int lane = t & 63;
    const int wave = t >> 6;
    const int col  = lane & 15;    // MFMA n-index
    const int quad = lane >> 4;    // MFMA k/row group
    const int wy = wave >> 1, wx = wave & 1;

    for (int tile = 0; tile < 16; ++tile) {
        const int buf = tile & 1;

        // ---- commit prefetched emb rows to LDS (bf16) ----
        {
            short* dst = &EMB[buf][gr * SA + gq * 16];
            #pragma unroll
            for (int i = 0; i < 4; ++i) {
                short4 s;
                s.x = f2bf(pf[i].x); s.y = f2bf(pf[i].y);
                s.z = f2bf(pf[i].z); s.w = f2bf(pf[i].w);
                *(short4*)(dst + i * 4) = s;          // ds_write_b64
            }
        }
        __syncthreads();

        // ---- issue next tile's gather (global->VGPR, overlaps both GEMMs) ----
        if (tile < 15) {
            int b = b0base + (tile + 1) * 64 + gr;
            unsigned idx = (unsigned)(inputs[b * NF + f] + 1) % HASH;
            const float4* src = (const float4*)(tabf + (size_t)idx * EDIM) + gq * 4;
            pf[0] = src[0]; pf[1] = src[1]; pf[2] = src[2]; pf[3] = src[3];
        }

        // ---- GEMM1: D1[hid][m] = W1T x embT ; wave: hid in [wy*64,+64), m in [wx*32,+32)
        f32x4 acc1[4][2];
        #pragma unroll
        for (int ht = 0; ht < 4; ++ht)
            #pragma unroll
            for (int mt = 0; mt < 2; ++mt)
                acc1[ht][mt] = (f32x4){0.f, 0.f, 0.f, 0.f};

        #pragma unroll
        for (int k0 = 0; k0 < EDIM; k0 += 32) {
            bf16x8 a[4], bb[2];
            #pragma unroll
            for (int ht = 0; ht < 4; ++ht)
                a[ht] = *(const bf16x8*)&W1T[(wy * 64 + ht * 16 + col) * SA + k0 + quad * 8];
            #pragma unroll
            for (int mt = 0; mt < 2; ++mt)
                bb[mt] = *(const bf16x8*)&EMB[buf][(wx * 32 + mt * 16 + col) * SA + k0 + quad * 8];
            #pragma unroll
            for (int ht = 0; ht < 4; ++ht)
                #pragma unroll
                for (int mt = 0; mt < 2; ++mt)
                    acc1[ht][mt] = __builtin_amdgcn_mfma_f32_16x16x32_bf16(
                        a[ht], bb[mt], acc1[ht][mt], 0, 0, 0);
        }

        // epilogue: +b1, relu, bf16, pack 4 consecutive hid -> ds_write_b64 into H[m][h]
        #pragma unroll
        for (int ht = 0; ht < 4; ++ht) {
            f32x4 bias = *(const f32x4*)&b1s[wy * 64 + ht * 16 + quad * 4];
            #pragma unroll
            for (int mt = 0; mt < 2; ++mt) {
                int m = wx * 32 + mt * 16 + col;
                short4 hv;
                hv.x = f2bf(fmaxf(acc1[ht][mt][0] + bias[0], 0.f));
                hv.y = f2bf(fmaxf(acc1[ht][mt][1] + bias[1], 0.f));
                hv.z = f2bf(fmaxf(acc1[ht][mt][2] + bias[2], 0.f));
                hv.w = f2bf(fmaxf(acc1[ht][mt][3] + bias[3], 0.f));
                *(short4*)&Hs[m * SH + wy * 64 + ht * 16 + quad * 4] = hv;
            }
        }
        __syncthreads();

        // ---- GEMM2: D2[o][m] = W2T x H^T ; wave: o in [wy*32,+32), m in [wx*32,+32)
        f32x4 acc2[2][2];
        #pragma unroll
        for (int ot = 0; ot < 2; ++ot)
            #pragma unroll
            for (int mt = 0; mt < 2; ++mt)
                acc2[ot][mt] = (f32x4){0.f, 0.f, 0.f, 0.f};

        #pragma unroll
        for (int k0 = 0; k0 < HID; k0 += 32) {
            bf16x8 a[2], bb[2];
            #pragma unroll
            for (int ot = 0; ot < 2; ++ot)
                a[ot] = *(const bf16x8*)&W2T[(wy * 32 + ot * 16 + col) * SH + k0 + quad * 8];
            #pragma unroll
            for (int mt = 0; mt < 2; ++mt)
                bb[mt] = *(const bf16x8*)&Hs[(wx * 32 + mt * 16 + col) * SH + k0 + quad * 8];
            #pragma unroll
            for (int ot = 0; ot < 2; ++ot)
                #pragma unroll
                for (int mt = 0; mt < 2; ++mt)
                    acc2[ot][mt] = __builtin_amdgcn_mfma_f32_16x16x32_bf16(
                        a[ot], bb[mt], acc2[ot][mt], 0, 0, 0);
        }

        // epilogue: +b2, float4 store (4 consecutive o per lane)
        {
            const size_t outbase = (size_t)f * BSZ;
            #pragma unroll
            for (int ot = 0; ot < 2; ++ot) {
                f32x4 bv = *(const f32x4*)&b2s[wy * 32 + ot * 16 + quad * 4];
                #pragma unroll
                for (int mt = 0; mt < 2; ++mt) {
                    int m = wx * 32 + mt * 16 + col;
                    size_t b = (size_t)b0base + (size_t)tile * 64 + m;
                    float4 ov;
                    ov.x = acc2[ot][mt][0] + bv[0];
                    ov.y = acc2[ot][mt][1] + bv[1];
                    ov.z = acc2[ot][mt][2] + bv[2];
                    ov.w = acc2[ot][mt][3] + bv[3];
                    *(float4*)&out[(outbase + b) * ODIM + wy * 32 + ot * 16 + quad * 4] = ov;
                }
            }
        }
        __syncthreads();
    }
}

extern "C" void kernel_launch(void* const* d_in, const int* in_sizes, int n_in,
                              void* d_out, int out_size, void* d_ws, size_t ws_size,
                              hipStream_t stream) {
    const int*   inputs = (const int*)d_in[0];
    const float* tables = (const float*)d_in[1];
    const float* W1     = (const float*)d_in[2];
    const float* b1     = (const float*)d_in[3];
    const float* W2     = (const float*)d_in[4];
    const float* b2     = (const float*)d_in[5];
    float* out = (float*)d_out;
    sparse_arch_kernel<<<dim3(NF * 32), dim3(256), 0, stream>>>(
        inputs, tables, W1, b1, W2, b2, out);
}